// Round 17
// baseline (406.384 us; speedup 1.0000x reference)
//
#include <hip/hip_runtime.h>
#include <hip/hip_bf16.h>
#include <cstdint>

#define S_LEN 2048
#define HIDN  2048
#define NH    32
#define NKV   8
#define HD    64
#define FFN   8192
#define QKVN  3072   // 2048 q + 512 k + 512 v
#define QKVLD 3072

typedef __attribute__((ext_vector_type(4)))  float f32x4;
typedef __attribute__((ext_vector_type(16))) float f32x16;
typedef __attribute__((ext_vector_type(8)))  short short8;
typedef __attribute__((ext_vector_type(4)))  short s16x4;

__device__ __forceinline__ short f2bf(float f) {
  union { float f; uint32_t u; } v; v.f = f;
  uint32_t r = v.u + 0x7FFFu + ((v.u >> 16) & 1u);
  return (short)(r >> 16);
}
__device__ __forceinline__ float bf2f(short s) {
  union { float f; uint32_t u; } v; v.u = ((uint32_t)(uint16_t)s) << 16;
  return v.f;
}
__device__ __forceinline__ unsigned packbf2(float lo, float hi) {
  return (unsigned)(uint16_t)f2bf(lo) | ((unsigned)(uint16_t)f2bf(hi) << 16);
}
__device__ __forceinline__ unsigned packs2(short lo, short hi) {
  return (unsigned)(uint16_t)lo | ((unsigned)(uint16_t)hi << 16);
}

#define GLOAD_LDS16(gp, lp) \
  __builtin_amdgcn_global_load_lds((const __attribute__((address_space(1))) void*)(gp), \
                                   (__attribute__((address_space(3))) void*)(lp), 16, 0, 0)

#define BARRIER()  asm volatile("s_barrier" ::: "memory")
#define LGKM0()    asm volatile("s_waitcnt lgkmcnt(0)" ::: "memory")
#define SCHED0()   __builtin_amdgcn_sched_barrier(0)
#define VMCNT(N)   asm volatile("s_waitcnt vmcnt(%0)" :: "n"(N) : "memory")

// ---------------- transpose-convert: fp32 [K][N] -> bf16 [N][K] ----------------
__device__ __forceinline__ void convT_body(const float* __restrict__ src,
    short* __restrict__ dst, int K, int N, int bx, int by, int tidx) {
  __shared__ float t[64][65];
  const int k0 = bx * 64, n0 = by * 64;
  const int tr = tidx >> 4, tc = (tidx & 15) * 4;
  #pragma unroll
  for (int i = 0; i < 4; ++i) {
    float4 v = *(const float4*)(src + (size_t)(k0 + tr + i * 16) * N + n0 + tc);
    t[tr + i * 16][tc] = v.x; t[tr + i * 16][tc + 1] = v.y;
    t[tr + i * 16][tc + 2] = v.z; t[tr + i * 16][tc + 3] = v.w;
  }
  __syncthreads();
  const int dr = tidx >> 2, dc = (tidx & 3) * 16;
  short8 o0, o1;
  #pragma unroll
  for (int j = 0; j < 8; ++j) { o0[j] = f2bf(t[dc + j][dr]); o1[j] = f2bf(t[dc + 8 + j][dr]); }
  short* dp = dst + (size_t)(n0 + dr) * K + k0 + dc;
  *(short8*)dp = o0;
  *(short8*)(dp + 8) = o1;
}

__global__ __launch_bounds__(256) void convT_kernel(const float* __restrict__ src,
    short* __restrict__ dst, int K, int N) {
  convT_body(src, dst, K, N, blockIdx.x, blockIdx.y, threadIdx.x);
}

// ---- merged QKV+WO weight convert: z=0 wq, z=1 wk, z=2 wv, z=3 wo ----
__global__ __launch_bounds__(256) void convT4_kernel(const float* __restrict__ wq,
    const float* __restrict__ wk, const float* __restrict__ wv,
    const float* __restrict__ wo, short* __restrict__ Wqkv, short* __restrict__ Wwo) {
  const int z = blockIdx.z;
  if (z == 0) {
    convT_body(wq, Wqkv, HIDN, NH * HD, blockIdx.x, blockIdx.y, threadIdx.x);
  } else if (z == 1) {
    if (blockIdx.y < 8)
      convT_body(wk, Wqkv + (size_t)2048 * HIDN, HIDN, NKV * HD, blockIdx.x, blockIdx.y, threadIdx.x);
  } else if (z == 2) {
    if (blockIdx.y < 8)
      convT_body(wv, Wqkv + (size_t)2560 * HIDN, HIDN, NKV * HD, blockIdx.x, blockIdx.y, threadIdx.x);
  } else {
    convT_body(wo, Wwo, NH * HD, HIDN, blockIdx.x, blockIdx.y, threadIdx.x);
  }
}

// ---- gate/up transpose + interleave pack (both planes in one launch) ----
__global__ __launch_bounds__(256) void convT_pack2_kernel(const float* __restrict__ wg,
    const float* __restrict__ wu, short* __restrict__ dst) {
  __shared__ float t[64][65];
  const int plane = blockIdx.z;
  const float* src = plane ? wu : wg;
  const int k0 = blockIdx.x * 64, n0 = blockIdx.y * 64;
  const int tr = threadIdx.x >> 4, tc = (threadIdx.x & 15) * 4;
  #pragma unroll
  for (int i = 0; i < 4; ++i) {
    float4 v = *(const float4*)(src + (size_t)(k0 + tr + i * 16) * FFN + n0 + tc);
    t[tr + i * 16][tc] = v.x; t[tr + i * 16][tc + 1] = v.y;
    t[tr + i * 16][tc + 2] = v.z; t[tr + i * 16][tc + 3] = v.w;
  }
  __syncthreads();
  const int dr = threadIdx.x >> 2, dc = (threadIdx.x & 3) * 16;
  const int n = n0 + dr;
  const int rr = ((n >> 4) << 5) + plane * 16 + (n & 15);
  short8 o0, o1;
  #pragma unroll
  for (int j = 0; j < 8; ++j) { o0[j] = f2bf(t[dc + j][dr]); o1[j] = f2bf(t[dc + 8 + j][dr]); }
  short* dp = dst + (size_t)rr * HIDN + k0 + dc;
  *(short8*)dp = o0;
  *(short8*)(dp + 8) = o1;
}

// ---------------- RMSNorm: fp32 in -> bf16 out ----------------
__global__ __launch_bounds__(256) void rmsnorm_kernel(const float* __restrict__ X,
    const float* __restrict__ W, short* __restrict__ Y) {
  int row = blockIdx.x;
  const float4* x4 = (const float4*)(X + (size_t)row * HIDN);
  const float4* w4 = (const float4*)W;
  float4 v0 = x4[2 * threadIdx.x];
  float4 v1 = x4[2 * threadIdx.x + 1];
  float ss = v0.x*v0.x + v0.y*v0.y + v0.z*v0.z + v0.w*v0.w
           + v1.x*v1.x + v1.y*v1.y + v1.z*v1.z + v1.w*v1.w;
  #pragma unroll
  for (int off = 32; off > 0; off >>= 1) ss += __shfl_xor(ss, off, 64);
  __shared__ float red[4];
  if ((threadIdx.x & 63) == 0) red[threadIdx.x >> 6] = ss;
  __syncthreads();
  ss = red[0] + red[1] + red[2] + red[3];
  float rs = rsqrtf(ss * (1.0f / HIDN) + 1e-5f);
  float4 w0 = w4[2 * threadIdx.x], w1 = w4[2 * threadIdx.x + 1];
  short8 o;
  o[0] = f2bf(v0.x * rs * w0.x); o[1] = f2bf(v0.y * rs * w0.y);
  o[2] = f2bf(v0.z * rs * w0.z); o[3] = f2bf(v0.w * rs * w0.w);
  o[4] = f2bf(v1.x * rs * w1.x); o[5] = f2bf(v1.y * rs * w1.y);
  o[6] = f2bf(v1.z * rs * w1.z); o[7] = f2bf(v1.w * rs * w1.w);
  *(short8*)(Y + (size_t)row * HIDN + threadIdx.x * 8) = o;
}

// ---- fused: out = hs + P0 + P1 (fp32), y = rmsnorm(out)*w (bf16). One row/block.
__global__ __launch_bounds__(256) void wo_norm_kernel(float* __restrict__ out,
    const float* __restrict__ hs, const short* __restrict__ P,
    const float* __restrict__ W, short* __restrict__ Y) {
  const size_t n = (size_t)S_LEN * HIDN;
  const int row = blockIdx.x;
  const size_t base = (size_t)row * HIDN + threadIdx.x * 8;
  float4 h0 = *(const float4*)(hs + base);
  float4 h1 = *(const float4*)(hs + base + 4);
  short8 a = *(const short8*)(P + base);
  short8 b = *(const short8*)(P + n + base);
  float v[8];
  v[0] = h0.x + bf2f(a[0]) + bf2f(b[0]);
  v[1] = h0.y + bf2f(a[1]) + bf2f(b[1]);
  v[2] = h0.z + bf2f(a[2]) + bf2f(b[2]);
  v[3] = h0.w + bf2f(a[3]) + bf2f(b[3]);
  v[4] = h1.x + bf2f(a[4]) + bf2f(b[4]);
  v[5] = h1.y + bf2f(a[5]) + bf2f(b[5]);
  v[6] = h1.z + bf2f(a[6]) + bf2f(b[6]);
  v[7] = h1.w + bf2f(a[7]) + bf2f(b[7]);
  float4 o0 = {v[0], v[1], v[2], v[3]}, o1 = {v[4], v[5], v[6], v[7]};
  *(float4*)(out + base) = o0;
  *(float4*)(out + base + 4) = o1;
  float ss = 0.f;
  #pragma unroll
  for (int j = 0; j < 8; ++j) ss += v[j] * v[j];
  #pragma unroll
  for (int off = 32; off > 0; off >>= 1) ss += __shfl_xor(ss, off, 64);
  __shared__ float red[4];
  if ((threadIdx.x & 63) == 0) red[threadIdx.x >> 6] = ss;
  __syncthreads();
  ss = red[0] + red[1] + red[2] + red[3];
  float rs = rsqrtf(ss * (1.0f / HIDN) + 1e-5f);
  float4 w0 = *(const float4*)(W + threadIdx.x * 8);
  float4 w1 = *(const float4*)(W + threadIdx.x * 8 + 4);
  short8 o;
  o[0] = f2bf(v[0] * rs * w0.x); o[1] = f2bf(v[1] * rs * w0.y);
  o[2] = f2bf(v[2] * rs * w0.z); o[3] = f2bf(v[3] * rs * w0.w);
  o[4] = f2bf(v[4] * rs * w1.x); o[5] = f2bf(v[5] * rs * w1.y);
  o[6] = f2bf(v[6] * rs * w1.z); o[7] = f2bf(v[7] * rs * w1.w);
  *(short8*)(Y + base) = o;
}

// ============ gemm8p: 256xBN tile, BK=64, 8 waves, 8-phase depth-3 pipeline ==
// Staging via 8 precomputed per-thread pointers advanced by +64/stage (same
// addresses as before, ~1 VALU add per stage instead of full 64-bit recompute).
// EPI 0: bf16=acc | 1: f32=acc+Xf32 | 4: fused gate/up silu(g)*u -> bf16 [M][N/2]
// EPI 5: bf16 partial (split-K) at z*M*N
template<int EPI, int BN>
__global__ __launch_bounds__(512, 1) void gemm8p(const short* __restrict__ A,
    const short* __restrict__ BT, void* __restrict__ Cp, const void* __restrict__ Xp,
    int N, int Kfull, int KC, int gy) {
  constexpr int NFN = BN / 64;
  constexpr int LB  = BN / 128;
  constexpr int VN  = 2 + 2 * LB;
  __shared__ __align__(16) short As[2][256 * 64];
  __shared__ __align__(16) short Bs[2][BN * 64];
  const int tid = threadIdx.x, lane = tid & 63, w = tid >> 6;
  const int wm2 = w >> 2;
  const int wn = (w & 3) * (BN / 4);
  const int l15 = lane & 15, lg = lane >> 4;
  const int cpx = gy >> 3;
  const int xcd = blockIdx.x & 7, cid = blockIdx.x >> 3;
  const int by = xcd * cpx + cid % cpx, bx = cid / cpx;
  const int brow = bx * 256, bcol = by * BN;
  const size_t kbase = (size_t)blockIdx.z * KC;
  const int r8 = lane >> 3, c8 = lane & 7;
  const int gblk = c8 ^ r8;
  const int nt = KC / 64;
  f32x4 acc[8][NFN] = {};
  short8 af[4], bf[2][NFN];

  // per-unit staging pointers (advance +64 shorts per stage)
  const short* gpa[2][2];
  const short* gpb[2][LB];
  #pragma unroll
  for (int h = 0; h < 2; ++h)
    #pragma unroll
    for (int j = 0; j < 2; ++j)
      gpa[h][j] = A + (size_t)(brow + h * 128 + j * 64 + w * 8 + r8) * Kfull + kbase + gblk * 8;
  #pragma unroll
  for (int h = 0; h < 2; ++h)
    #pragma unroll
    for (int j = 0; j < LB; ++j)
      gpb[h][j] = BT + (size_t)(bcol + h * (BN / 2) + j * 64 + w * 8 + r8) * Kfull + kbase + gblk * 8;

  auto STA = [&](int p, int h) {
    #pragma unroll
    for (int j = 0; j < 2; ++j) {
      GLOAD_LDS16(gpa[h][j], &As[p][(h * 128 + j * 64 + w * 8) * 64]);
      gpa[h][j] += 64;
    }
  };
  auto STB = [&](int p, int h) {
    #pragma unroll
    for (int j = 0; j < LB; ++j) {
      GLOAD_LDS16(gpb[h][j], &Bs[p][(h * (BN / 2) + j * 64 + w * 8) * 64]);
      gpb[h][j] += 64;
    }
  };
  auto LDA = [&](int p, int mh, int kk) {
    #pragma unroll
    for (int m = 0; m < 4; ++m) {
      const int row = mh * 128 + wm2 * 64 + m * 16 + l15;
      af[m] = *(const short8*)&As[p][row * 64 + (((kk * 4 + lg) ^ (row & 7)) * 8)];
    }
  };
  auto LDB = [&](int p, int kk) {
    #pragma unroll
    for (int n = 0; n < NFN; ++n) {
      const int row = wn + n * 16 + l15;
      bf[kk][n] = *(const short8*)&Bs[p][row * 64 + (((kk * 4 + lg) ^ (row & 7)) * 8)];
    }
  };

#define MMQ(MH, KK) \
  __builtin_amdgcn_s_setprio(1); \
  _Pragma("unroll") \
  for (int m = 0; m < 4; ++m) \
    _Pragma("unroll") \
    for (int n = 0; n < NFN; ++n) \
      acc[(MH) * 4 + m][n] = __builtin_amdgcn_mfma_f32_16x16x32_bf16(af[m], bf[KK][n], acc[(MH) * 4 + m][n], 0, 0, 0); \
  __builtin_amdgcn_s_setprio(0);

  // prologue: T0 fully (B0,B1,A0,A1), T1 partial (B0,B1,A0); wait T0 only
  STB(0, 0); STB(0, 1); STA(0, 0); STA(0, 1);
  STB(1, 0); STB(1, 1); STA(1, 0);
  VMCNT(VN);
  BARRIER();

  for (int i = 0; i < nt / 2; ++i) {
    const bool li = (i == nt / 2 - 1);
    // ph1: read buf0 {A0 k0, B k0+k1}; stage A1(t+1)
    LDA(0, 0, 0); LDB(0, 0); LDB(0, 1);
    STA(1, 1);
    BARRIER(); LGKM0(); SCHED0();
    MMQ(0, 0);
    BARRIER();
    // ph2: read A0 k1; stage B0(t+2)
    LDA(0, 0, 1);
    if (!li) STB(0, 0);
    BARRIER(); LGKM0(); SCHED0();
    MMQ(0, 1);
    BARRIER();
    // ph3: read A1 k0; stage B1(t+2)
    LDA(0, 1, 0);
    if (!li) STB(0, 1);
    BARRIER(); LGKM0(); SCHED0();
    MMQ(1, 0);
    BARRIER();
    // ph4: read A1 k1; stage A0(t+2); vmcnt
    LDA(0, 1, 1);
    if (!li) STA(0, 0);
    BARRIER(); LGKM0(); SCHED0();
    MMQ(1, 1);
    if (li) { VMCNT(0); } else { VMCNT(VN); }
    BARRIER();
    // ph5: read buf1 {A0 k0, B k0+k1}; stage A1(t+2)
    LDA(1, 0, 0); LDB(1, 0); LDB(1, 1);
    if (!li) STA(0, 1);
    BARRIER(); LGKM0(); SCHED0();
    MMQ(0, 0);
    BARRIER();
    // ph6: read A0 k1; stage B0(t+3)
    LDA(1, 0, 1);
    if (!li) STB(1, 0);
    BARRIER(); LGKM0(); SCHED0();
    MMQ(0, 1);
    BARRIER();
    // ph7: read A1 k0; stage B1(t+3)
    LDA(1, 1, 0);
    if (!li) STB(1, 1);
    BARRIER(); LGKM0(); SCHED0();
    MMQ(1, 0);
    BARRIER();
    // ph8: read A1 k1; stage A0(t+3); vmcnt
    LDA(1, 1, 1);
    if (!li) STA(1, 0);
    BARRIER(); LGKM0(); SCHED0();
    MMQ(1, 1);
    if (!li) { VMCNT(VN); }
    BARRIER();
  }
#undef MMQ

  if (EPI == 4) {
    const int No = N >> 1;
    #pragma unroll
    for (int mf = 0; mf < 8; ++mf) {
      const int r0 = brow + (mf >> 2) * 128 + wm2 * 64 + (mf & 3) * 16 + lg * 4;
      #pragma unroll
      for (int jg = 0; jg < NFN / 2; ++jg) {
        const int c = (bcol >> 1) + (wn >> 1) + jg * 16 + l15;
        #pragma unroll
        for (int i4 = 0; i4 < 4; ++i4) {
          float gt = acc[mf][2 * jg][i4];
          float up = acc[mf][2 * jg + 1][i4];
          ((short*)Cp)[(size_t)(r0 + i4) * No + c] = f2bf(gt / (1.f + __expf(-gt)) * up);
        }
      }
    }
  } else {
    #pragma unroll
    for (int mf = 0; mf < 8; ++mf) {
      const int r0 = brow + (mf >> 2) * 128 + wm2 * 64 + (mf & 3) * 16 + lg * 4;
      #pragma unroll
      for (int nf = 0; nf < NFN; ++nf) {
        const int c = bcol + wn + nf * 16 + l15;
        #pragma unroll
        for (int i4 = 0; i4 < 4; ++i4) {
          const size_t idx = (size_t)(r0 + i4) * N + c;
          float v = acc[mf][nf][i4];
          if (EPI == 0) ((short*)Cp)[idx] = f2bf(v);
          if (EPI == 1) ((float*)Cp)[idx] = v + ((const float*)Xp)[idx];
          if (EPI == 5) ((short*)Cp)[(size_t)blockIdx.z * S_LEN * N + idx] = f2bf(v);
        }
      }
    }
  }
}

// ---------------- RoPE (in-place, K heads only; Q rope fused into attn) ----
__global__ __launch_bounds__(256) void rope_k_kernel(short* __restrict__ qkv,
    const float* __restrict__ cosb, const float* __restrict__ sinb) {
  int idx = blockIdx.x * 256 + threadIdx.x;
  int d = idx & 31;
  int hh = (idx >> 5) & (NKV - 1);
  int s = idx >> 8;
  short* base = qkv + (size_t)s * QKVLD + HIDN + hh * HD;
  float c  = cosb[s * HD + d];
  float sn = sinb[s * HD + d];
  float x1 = bf2f(base[d]), x2 = bf2f(base[d + 32]);
  base[d]      = f2bf(x1 * c - x2 * sn);
  base[d + 32] = f2bf(x2 * c + x1 * sn);
}

// ---------------- Flash attention: swapped 32x32x16, KVBLK=128, fused Q-rope,
// XOR-swizzled K/V LDS (conflict-free reads), paired-b32 V-transpose writes ----
__global__ __launch_bounds__(256) void attn_kernel(const short* __restrict__ QKV,
    const float* __restrict__ cosb, const float* __restrict__ sinb,
    short* __restrict__ O) {
  __shared__ __align__(16) short Ks[128 * 64];   // row-major, 16B-block swizzle ^(row&7)
  __shared__ __align__(16) short VTs[64 * 128];  // [d][k], 16B-block swizzle ^(d&7)
  const int bid = blockIdx.x;
  const int half_ = bid >> 8, idx = bid & 255;
  const int h = idx & 31;
  int qt = idx >> 5;
  qt = half_ ? (15 - qt) : qt;
  const int kvh = h >> 2;
  const int tid = threadIdx.x, lane = tid & 63, w = tid >> 6;
  const int l31 = lane & 31, hi = lane >> 5;
  const int qb = qt * 128 + w * 32;
  const int kcol = HIDN + kvh * HD;
  const int vcol = HIDN + NKV * HD + kvh * HD;

  // Q load + fused rope + 1/8 scale
  short8 Qr[4];
  {
    const int s = qb + l31;
    const short* qp = QKV + (size_t)s * QKVLD + h * HD;
    short8 qv[4];
    #pragma unroll
    for (int dk = 0; dk < 4; ++dk) qv[dk] = *(const short8*)(qp + dk * 16 + hi * 8);
    const float* cp = cosb + s * HD;
    const float* sp = sinb + s * HD;
    #pragma unroll
    for (int dk = 0; dk < 2; ++dk)
      #pragma unroll
      for (int e = 0; e < 8; ++e) {
        const int d = dk * 16 + hi * 8 + e;
        float c = cp[d], sn = sp[d];
        float x1 = bf2f(qv[dk][e]), x2 = bf2f(qv[dk + 2][e]);
        Qr[dk][e]     = f2bf((x1 * c - x2 * sn) * 0.125f);
        Qr[dk + 2][e] = f2bf((x2 * c + x1 * sn) * 0.125f);
      }
  }
  float m_ = -3e38f, l_ = 0.f;
  f32x16 o0 = {}, o1 = {};
  const int nt = qt + 1;               // 128-wide KV tiles
  const int kr_ = tid >> 1, kdb1 = (tid & 1);
  const int va_ = tid & 63, vdb = (tid >> 6) * 16;

  short8 kp0, kp1, kp2, kp3, vp0, vp1, vp2, vp3;
  {
    const short* gk = QKV + (size_t)kr_ * QKVLD + kcol + kdb1 * 32;
    kp0 = *(const short8*)gk;        kp1 = *(const short8*)(gk + 8);
    kp2 = *(const short8*)(gk + 16); kp3 = *(const short8*)(gk + 24);
    const short* gv0 = QKV + (size_t)(2 * va_) * QKVLD + vcol + vdb;
    const short* gv1 = QKV + (size_t)(2 * va_ + 1) * QKVLD + vcol + vdb;
    vp0 = *(const short8*)gv0; vp1 = *(const short8*)(gv0 + 8);
    vp2 = *(const short8*)gv1; vp3 = *(const short8*)(gv1 + 8);
  }

  for (int t = 0; t < nt; ++t) {
    const int kb = t * 128;
    BARRIER();                     // prev compute done
    {
      short* kbase_ = Ks + kr_ * 64;
      const int rs = kr_ & 7;
      *(short8*)(kbase_ + ((kdb1 * 4 + 0) ^ rs) * 8) = kp0;
      *(short8*)(kbase_ + ((kdb1 * 4 + 1) ^ rs) * 8) = kp1;
      *(short8*)(kbase_ + ((kdb1 * 4 + 2) ^ rs) * 8) = kp2;
      *(short8*)(kbase_ + ((kdb1 * 4 + 3) ^ rs) * 8) = kp3;
      const int kblk = (2 * va_) >> 3, kin = (2 * va_) & 7;
      #pragma unroll
      for (int j = 0; j < 8; ++j) {
        const int d0 = vdb + j;
        *(unsigned*)(VTs + d0 * 128 + ((kblk ^ (d0 & 7)) * 8) + kin) = packs2(vp0[j], vp2[j]);
        const int d1 = vdb + 8 + j;
        *(unsigned*)(VTs + d1 * 128 + ((kblk ^ (d1 & 7)) * 8) + kin) = packs2(vp1[j], vp3[j]);
      }
    }
    LGKM0();                       // LDS writes visible
    BARRIER();
    if (t + 1 < nt) {              // async prefetch next tile under compute
      const int kb2 = kb + 128;
      const short* gk = QKV + (size_t)(kb2 + kr_) * QKVLD + kcol + kdb1 * 32;
      kp0 = *(const short8*)gk;        kp1 = *(const short8*)(gk + 8);
      kp2 = *(const short8*)(gk + 16); kp3 = *(const short8*)(gk + 24);
      const short* gv0 = QKV + (size_t)(kb2 + 2 * va_) * QKVLD + vcol + vdb;
      const short* gv1 = QKV + (size_t)(kb2 + 2 * va_ + 1) * QKVLD + vcol + vdb;
      vp0 = *(const short8*)gv0; vp1 = *(const short8*)(gv0 + 8);
      vp2 = *(const short8*)gv1; vp3 = *(const short8*)(gv1 + 8);
    }
    #pragma unroll
    for (int hf = 0; hf < 2; ++hf) {
      const int hb = kb + hf * 64;
      if (hb < qb + 32) {
        f32x16 s[2] = {};
        __builtin_amdgcn_s_setprio(1);
        #pragma unroll
        for (int kt = 0; kt < 2; ++kt) {
          const int row = hf * 64 + kt * 32 + l31;
          #pragma unroll
          for (int dk = 0; dk < 4; ++dk) {
            short8 kf = *(const short8*)(Ks + row * 64 + (((dk * 2 + hi) ^ (row & 7)) * 8));
            s[kt] = __builtin_amdgcn_mfma_f32_32x32x16_bf16(kf, Qr[dk], s[kt], 0, 0, 0);
          }
        }
        __builtin_amdgcn_s_setprio(0);
        if (hb + 63 > qb) {
          const int qg = qb + l31;
          #pragma unroll
          for (int kt = 0; kt < 2; ++kt)
            #pragma unroll
            for (int r = 0; r < 16; ++r) {
              const int kg = hb + kt * 32 + (r & 3) + 8 * (r >> 2) + 4 * hi;
              if (kg > qg) s[kt][r] = -1e30f;
            }
        }
        float pm = s[0][0];
        #pragma unroll
        for (int r = 1; r < 16; ++r) pm = fmaxf(pm, s[0][r]);
        #pragma unroll
        for (int r = 0; r < 16; ++r) pm = fmaxf(pm, s[1][r]);
        pm = fmaxf(pm, __shfl_xor(pm, 32));
        const float mn = fmaxf(m_, pm);
        const float al = __expf(m_ - mn);
        float rsum = 0.f;
        #pragma unroll
        for (int kt = 0; kt < 2; ++kt)
          #pragma unroll
          for (int r = 0; r < 16; ++r) { s[kt][r] = __expf(s[kt][r] - mn); rsum += s[kt][r]; }
        rsum += __shfl_xor(rsum, 32);
        l_ = l_ * al + rsum;
        m_ = mn;
        o0 *= al; o1 *= al;
        unsigned wd[2][8], rw[2][8];
        #pragma unroll
        for (int kt = 0; kt < 2; ++kt)
          #pragma unroll
          for (int i = 0; i < 8; ++i) {
            wd[kt][i] = packbf2(s[kt][2 * i], s[kt][2 * i + 1]);
            rw[kt][i] = (unsigned)__shfl_xor((int)wd[kt][i], 32);
          }
        #pragma unroll
        for (int kt = 0; kt < 2; ++kt) {
          union { unsigned u[4]; short8 s8; } pf0, pf1;
          if (hi) {
            pf0.u[0] = rw[kt][2]; pf0.u[1] = rw[kt][3]; pf0.u[2] = wd[kt][2]; pf0.u[3] = wd[kt][3];
            pf1.u[0] = rw[kt][6]; pf1.u[1] = rw[kt][7]; pf1.u[2] = wd[kt][6]; pf1.u[3] = wd[kt][7];
          } else {
            pf0.u[0] = wd[kt][0]; pf0.u[1] = wd[kt][1]; pf0.u[2] = rw[kt][0]; pf0.u[3] = rw[kt][1];
            pf1.u[0] = wd[kt][4]; pf1.u[1] = wd[kt][5]; pf1.u[2] = rw[kt][4]; pf1.u[3] = rw[kt][5];
          }
          __builtin_amdgcn_s_setprio(1);
          #pragma unroll
          for (int ks = 0; ks < 2; ++ks) {
            const short8 pB = ks ? pf1.s8 : pf0.s8;
            const int blk = hf * 8 + kt * 4 + ks * 2 + hi;
            const int d0 = l31, d1 = 32 + l31;
            short8 va = *(const short8*)(VTs + d0 * 128 + ((blk ^ (d0 & 7)) * 8));
            o0 = __builtin_amdgcn_mfma_f32_32x32x16_bf16(va, pB, o0, 0, 0, 0);
            short8 vb = *(const short8*)(VTs + d1 * 128 + ((blk ^ (d1 & 7)) * 8));
            o1 = __builtin_amdgcn_mfma_f32_32x32x16_bf16(vb, pB, o1, 0, 0, 0);
          }
          __builtin_amdgcn_s_setprio(0);
        }
      }
    }
  }
  const float inv = 1.f / l_;
  short* op = O + (size_t)(qb + l31) * HIDN + h * HD;
  #pragma unroll
  for (int dt = 0; dt < 2; ++dt) {
    const f32x16& o = dt ? o1 : o0;
    #pragma unroll
    for (int g = 0; g < 4; ++g) {
      s16x4 st;
      st[0] = f2bf(o[g * 4 + 0] * inv);
      st[1] = f2bf(o[g * 4 + 1] * inv);
      st[2] = f2bf(o[g * 4 + 2] * inv);
      st[3] = f2bf(o[g * 4 + 3] * inv);
      *(s16x4*)(op + dt * 32 + g * 8 + hi * 4) = st;
    }
  }
}

// ---------------- out += sum of 4 bf16 split-K partials ----------------
__global__ __launch_bounds__(256) void reduce4_kernel(float* __restrict__ out,
    const short* __restrict__ P) {
  const size_t n = (size_t)S_LEN * HIDN;
  size_t i = ((size_t)blockIdx.x * 256 + threadIdx.x) * 4;
  float4 o = *(float4*)(out + i);
  float s0 = 0.f, s1 = 0.f, s2 = 0.f, s3 = 0.f;
  #pragma unroll
  for (int z = 0; z < 4; ++z) {
    s16x4 p = *(const s16x4*)(P + z * n + i);
    s0 += bf2f(p[0]); s1 += bf2f(p[1]); s2 += bf2f(p[2]); s3 += bf2f(p[3]);
  }
  o.x += s0; o.y += s1; o.z += s2; o.w += s3;
  *(float4*)(out + i) = o;
}

extern "C" void kernel_launch(void* const* d_in, const int* in_sizes, int n_in,
                              void* d_out, int out_size, void* d_ws, size_t ws_size,
                              hipStream_t stream) {
  const float* hs   = (const float*)d_in[0];
  const float* cosb = (const float*)d_in[1];
  const float* sinb = (const float*)d_in[2];
  const float* wq   = (const float*)d_in[3];
  const float* wk   = (const float*)d_in[4];
  const float* wv   = (const float*)d_in[5];
  const float* wo   = (const float*)d_in[6];
  const float* wln1 = (const float*)d_in[7];
  const float* wln2 = (const float*)d_in[8];
  const float* wg   = (const float*)d_in[9];
  const float* wu   = (const float*)d_in[10];
  const float* wd   = (const float*)d_in[11];
  float* out = (float*)d_out;
  char* ws = (char*)d_ws;
  const size_t MB = 1024 * 1024;
  // ws layout (104 MB, R13-verified):
  //  Wqkv@0 (12.6) -> dead after QKV gemm; Pwo@0 (16) after attn; Wbig@0 (64); Wd@0 (32)
  //  xn@13 (8) -> dead after QKV gemm
  //  qkv@21 (12.6) -> dead after attn
  //  attnO@34 (8); Wwo@42 (8); y@64 (8); g@72 (32); P@32 (32, 4 bf16 planes)
  short* Wqkv  = (short*)(ws);
  short* xn    = (short*)(ws + 13 * MB);
  short* qkv   = (short*)(ws + 21 * MB);
  short* attnO = (short*)(ws + 34 * MB);
  short* Wwo   = (short*)(ws + 42 * MB);
  short* Pwo   = (short*)(ws);
  short* y     = (short*)(ws + 64 * MB);
  short* g     = (short*)(ws + 72 * MB);
  short* Wbig  = (short*)(ws);
  short* Wd    = (short*)(ws);
  short* P     = (short*)(ws + 32 * MB);

  convT4_kernel<<<dim3(32, 32, 4), 256, 0, stream>>>(wq, wk, wv, wo, Wqkv, Wwo);
  rmsnorm_kernel<<<S_LEN, 256, 0, stream>>>(hs, wln1, xn);
  gemm8p<0, 128><<<dim3(192, 1, 1), 512, 0, stream>>>(xn, Wqkv, qkv, nullptr, QKVN, HIDN, HIDN, 24);
  rope_k_kernel<<<(S_LEN * NKV * 32) / 256, 256, 0, stream>>>(qkv, cosb, sinb);
  attn_kernel<<<NH * (S_LEN / 128), 256, 0, stream>>>(qkv, cosb, sinb, attnO);
  gemm8p<5, 128><<<dim3(128, 1, 2), 512, 0, stream>>>(attnO, Wwo, Pwo, nullptr, HIDN, NH * HD, NH * HD / 2, 16);
  wo_norm_kernel<<<S_LEN, 256, 0, stream>>>(out, hs, Pwo, wln2, y);
  convT_pack2_kernel<<<dim3(32, 128, 2), 256, 0, stream>>>(wg, wu, Wbig);
  gemm8p<4, 256><<<dim3(512, 1, 1), 512, 0, stream>>>(y, Wbig, g, nullptr, 2 * FFN, HIDN, HIDN, 64);
  convT_kernel<<<dim3(128, 32), 256, 0, stream>>>(wd, Wd, FFN, HIDN);
  gemm8p<5, 256><<<dim3(64, 1, 4), 512, 0, stream>>>(g, Wd, P, nullptr, HIDN, FFN, FFN / 4, 8);
  reduce4_kernel<<<(S_LEN * HIDN) / 1024, 256, 0, stream>>>(out, P);
}

// Round 18
// 403.340 us; speedup vs baseline: 1.0075x; 1.0075x over previous
//
#include <hip/hip_runtime.h>
#include <hip/hip_bf16.h>
#include <cstdint>

#define S_LEN 2048
#define HIDN  2048
#define NH    32
#define NKV   8
#define HD    64
#define FFN   8192
#define QKVN  3072   // 2048 q + 512 k + 512 v
#define QKVLD 3072

typedef __attribute__((ext_vector_type(4)))  float f32x4;
typedef __attribute__((ext_vector_type(16))) float f32x16;
typedef __attribute__((ext_vector_type(8)))  short short8;
typedef __attribute__((ext_vector_type(4)))  short s16x4;

__device__ __forceinline__ short f2bf(float f) {
  union { float f; uint32_t u; } v; v.f = f;
  uint32_t r = v.u + 0x7FFFu + ((v.u >> 16) & 1u);
  return (short)(r >> 16);
}
__device__ __forceinline__ float bf2f(short s) {
  union { float f; uint32_t u; } v; v.u = ((uint32_t)(uint16_t)s) << 16;
  return v.f;
}
__device__ __forceinline__ unsigned packbf2(float lo, float hi) {
  return (unsigned)(uint16_t)f2bf(lo) | ((unsigned)(uint16_t)f2bf(hi) << 16);
}
__device__ __forceinline__ unsigned packs2(short lo, short hi) {
  return (unsigned)(uint16_t)lo | ((unsigned)(uint16_t)hi << 16);
}

#define GLOAD_LDS16(gp, lp) \
  __builtin_amdgcn_global_load_lds((const __attribute__((address_space(1))) void*)(gp), \
                                   (__attribute__((address_space(3))) void*)(lp), 16, 0, 0)

#define BARRIER()  asm volatile("s_barrier" ::: "memory")
#define LGKM0()    asm volatile("s_waitcnt lgkmcnt(0)" ::: "memory")
#define SCHED0()   __builtin_amdgcn_sched_barrier(0)
#define VMCNT(N)   asm volatile("s_waitcnt vmcnt(%0)" :: "n"(N) : "memory")

// ---------------- transpose-convert: fp32 [K][N] -> bf16 [N][K] ----------------
__device__ __forceinline__ void convT_body(const float* __restrict__ src,
    short* __restrict__ dst, int K, int N, int bx, int by, int tidx) {
  __shared__ float t[64][65];
  const int k0 = bx * 64, n0 = by * 64;
  const int tr = tidx >> 4, tc = (tidx & 15) * 4;
  #pragma unroll
  for (int i = 0; i < 4; ++i) {
    float4 v = *(const float4*)(src + (size_t)(k0 + tr + i * 16) * N + n0 + tc);
    t[tr + i * 16][tc] = v.x; t[tr + i * 16][tc + 1] = v.y;
    t[tr + i * 16][tc + 2] = v.z; t[tr + i * 16][tc + 3] = v.w;
  }
  __syncthreads();
  const int dr = tidx >> 2, dc = (tidx & 3) * 16;
  short8 o0, o1;
  #pragma unroll
  for (int j = 0; j < 8; ++j) { o0[j] = f2bf(t[dc + j][dr]); o1[j] = f2bf(t[dc + 8 + j][dr]); }
  short* dp = dst + (size_t)(n0 + dr) * K + k0 + dc;
  *(short8*)dp = o0;
  *(short8*)(dp + 8) = o1;
}

__global__ __launch_bounds__(256) void convT_kernel(const float* __restrict__ src,
    short* __restrict__ dst, int K, int N) {
  convT_body(src, dst, K, N, blockIdx.x, blockIdx.y, threadIdx.x);
}

// ---- merged QKV+WO weight convert: z=0 wq, z=1 wk, z=2 wv, z=3 wo ----
__global__ __launch_bounds__(256) void convT4_kernel(const float* __restrict__ wq,
    const float* __restrict__ wk, const float* __restrict__ wv,
    const float* __restrict__ wo, short* __restrict__ Wqkv, short* __restrict__ Wwo) {
  const int z = blockIdx.z;
  if (z == 0) {
    convT_body(wq, Wqkv, HIDN, NH * HD, blockIdx.x, blockIdx.y, threadIdx.x);
  } else if (z == 1) {
    if (blockIdx.y < 8)
      convT_body(wk, Wqkv + (size_t)2048 * HIDN, HIDN, NKV * HD, blockIdx.x, blockIdx.y, threadIdx.x);
  } else if (z == 2) {
    if (blockIdx.y < 8)
      convT_body(wv, Wqkv + (size_t)2560 * HIDN, HIDN, NKV * HD, blockIdx.x, blockIdx.y, threadIdx.x);
  } else {
    convT_body(wo, Wwo, NH * HD, HIDN, blockIdx.x, blockIdx.y, threadIdx.x);
  }
}

// ---- gate/up transpose + interleave pack (both planes in one launch) ----
__global__ __launch_bounds__(256) void convT_pack2_kernel(const float* __restrict__ wg,
    const float* __restrict__ wu, short* __restrict__ dst) {
  __shared__ float t[64][65];
  const int plane = blockIdx.z;
  const float* src = plane ? wu : wg;
  const int k0 = blockIdx.x * 64, n0 = blockIdx.y * 64;
  const int tr = threadIdx.x >> 4, tc = (threadIdx.x & 15) * 4;
  #pragma unroll
  for (int i = 0; i < 4; ++i) {
    float4 v = *(const float4*)(src + (size_t)(k0 + tr + i * 16) * FFN + n0 + tc);
    t[tr + i * 16][tc] = v.x; t[tr + i * 16][tc + 1] = v.y;
    t[tr + i * 16][tc + 2] = v.z; t[tr + i * 16][tc + 3] = v.w;
  }
  __syncthreads();
  const int dr = threadIdx.x >> 2, dc = (threadIdx.x & 3) * 16;
  const int n = n0 + dr;
  const int rr = ((n >> 4) << 5) + plane * 16 + (n & 15);
  short8 o0, o1;
  #pragma unroll
  for (int j = 0; j < 8; ++j) { o0[j] = f2bf(t[dc + j][dr]); o1[j] = f2bf(t[dc + 8 + j][dr]); }
  short* dp = dst + (size_t)rr * HIDN + k0 + dc;
  *(short8*)dp = o0;
  *(short8*)(dp + 8) = o1;
}

// ---------------- RMSNorm: fp32 in -> bf16 out ----------------
__global__ __launch_bounds__(256) void rmsnorm_kernel(const float* __restrict__ X,
    const float* __restrict__ W, short* __restrict__ Y) {
  int row = blockIdx.x;
  const float4* x4 = (const float4*)(X + (size_t)row * HIDN);
  const float4* w4 = (const float4*)W;
  float4 v0 = x4[2 * threadIdx.x];
  float4 v1 = x4[2 * threadIdx.x + 1];
  float ss = v0.x*v0.x + v0.y*v0.y + v0.z*v0.z + v0.w*v0.w
           + v1.x*v1.x + v1.y*v1.y + v1.z*v1.z + v1.w*v1.w;
  #pragma unroll
  for (int off = 32; off > 0; off >>= 1) ss += __shfl_xor(ss, off, 64);
  __shared__ float red[4];
  if ((threadIdx.x & 63) == 0) red[threadIdx.x >> 6] = ss;
  __syncthreads();
  ss = red[0] + red[1] + red[2] + red[3];
  float rs = rsqrtf(ss * (1.0f / HIDN) + 1e-5f);
  float4 w0 = w4[2 * threadIdx.x], w1 = w4[2 * threadIdx.x + 1];
  short8 o;
  o[0] = f2bf(v0.x * rs * w0.x); o[1] = f2bf(v0.y * rs * w0.y);
  o[2] = f2bf(v0.z * rs * w0.z); o[3] = f2bf(v0.w * rs * w0.w);
  o[4] = f2bf(v1.x * rs * w1.x); o[5] = f2bf(v1.y * rs * w1.y);
  o[6] = f2bf(v1.z * rs * w1.z); o[7] = f2bf(v1.w * rs * w1.w);
  *(short8*)(Y + (size_t)row * HIDN + threadIdx.x * 8) = o;
}

// ---- fused: out = hs + P0 + P1 (fp32), y = rmsnorm(out)*w (bf16). One row/block.
__global__ __launch_bounds__(256) void wo_norm_kernel(float* __restrict__ out,
    const float* __restrict__ hs, const short* __restrict__ P,
    const float* __restrict__ W, short* __restrict__ Y) {
  const size_t n = (size_t)S_LEN * HIDN;
  const int row = blockIdx.x;
  const size_t base = (size_t)row * HIDN + threadIdx.x * 8;
  float4 h0 = *(const float4*)(hs + base);
  float4 h1 = *(const float4*)(hs + base + 4);
  short8 a = *(const short8*)(P + base);
  short8 b = *(const short8*)(P + n + base);
  float v[8];
  v[0] = h0.x + bf2f(a[0]) + bf2f(b[0]);
  v[1] = h0.y + bf2f(a[1]) + bf2f(b[1]);
  v[2] = h0.z + bf2f(a[2]) + bf2f(b[2]);
  v[3] = h0.w + bf2f(a[3]) + bf2f(b[3]);
  v[4] = h1.x + bf2f(a[4]) + bf2f(b[4]);
  v[5] = h1.y + bf2f(a[5]) + bf2f(b[5]);
  v[6] = h1.z + bf2f(a[6]) + bf2f(b[6]);
  v[7] = h1.w + bf2f(a[7]) + bf2f(b[7]);
  float4 o0 = {v[0], v[1], v[2], v[3]}, o1 = {v[4], v[5], v[6], v[7]};
  *(float4*)(out + base) = o0;
  *(float4*)(out + base + 4) = o1;
  float ss = 0.f;
  #pragma unroll
  for (int j = 0; j < 8; ++j) ss += v[j] * v[j];
  #pragma unroll
  for (int off = 32; off > 0; off >>= 1) ss += __shfl_xor(ss, off, 64);
  __shared__ float red[4];
  if ((threadIdx.x & 63) == 0) red[threadIdx.x >> 6] = ss;
  __syncthreads();
  ss = red[0] + red[1] + red[2] + red[3];
  float rs = rsqrtf(ss * (1.0f / HIDN) + 1e-5f);
  float4 w0 = *(const float4*)(W + threadIdx.x * 8);
  float4 w1 = *(const float4*)(W + threadIdx.x * 8 + 4);
  short8 o;
  o[0] = f2bf(v[0] * rs * w0.x); o[1] = f2bf(v[1] * rs * w0.y);
  o[2] = f2bf(v[2] * rs * w0.z); o[3] = f2bf(v[3] * rs * w0.w);
  o[4] = f2bf(v[4] * rs * w1.x); o[5] = f2bf(v[5] * rs * w1.y);
  o[6] = f2bf(v[6] * rs * w1.z); o[7] = f2bf(v[7] * rs * w1.w);
  *(short8*)(Y + base) = o;
}

// ============ gemm8p: 256xBN tile, BK=64, 8 waves, 8-phase depth-3 pipeline ==
// EPI 0: bf16=acc | 1: f32=acc+Xf32 | 4: fused gate/up silu(g)*u -> bf16 [M][N/2]
// EPI 5: bf16 partial (split-K) at z*M*N
template<int EPI, int BN>
__global__ __launch_bounds__(512, 1) void gemm8p(const short* __restrict__ A,
    const short* __restrict__ BT, void* __restrict__ Cp, const void* __restrict__ Xp,
    int N, int Kfull, int KC, int gy) {
  constexpr int NFN = BN / 64;
  constexpr int LB  = BN / 128;
  constexpr int VN  = 2 + 2 * LB;
  __shared__ __align__(16) short As[2][256 * 64];
  __shared__ __align__(16) short Bs[2][BN * 64];
  const int tid = threadIdx.x, lane = tid & 63, w = tid >> 6;
  const int wm2 = w >> 2;
  const int wn = (w & 3) * (BN / 4);
  const int l15 = lane & 15, lg = lane >> 4;
  const int cpx = gy >> 3;
  const int xcd = blockIdx.x & 7, cid = blockIdx.x >> 3;
  const int by = xcd * cpx + cid % cpx, bx = cid / cpx;
  const int brow = bx * 256, bcol = by * BN;
  const size_t kbase = (size_t)blockIdx.z * KC;
  const int r8 = lane >> 3, c8 = lane & 7;
  const int gblk = c8 ^ r8;
  const int nt = KC / 64;
  f32x4 acc[8][NFN] = {};
  short8 af[4], bf[2][NFN];

  auto STA = [&](int p, int kt, int h) {
    const size_t kc = kbase + (size_t)kt * 64 + gblk * 8;
    #pragma unroll
    for (int j = 0; j < 2; ++j) {
      const short* g = A + (size_t)(brow + h * 128 + j * 64 + w * 8 + r8) * Kfull + kc;
      GLOAD_LDS16(g, &As[p][(h * 128 + j * 64 + w * 8) * 64]);
    }
  };
  auto STB = [&](int p, int kt, int h) {
    const size_t kc = kbase + (size_t)kt * 64 + gblk * 8;
    #pragma unroll
    for (int j = 0; j < LB; ++j) {
      const short* g = BT + (size_t)(bcol + h * (BN / 2) + j * 64 + w * 8 + r8) * Kfull + kc;
      GLOAD_LDS16(g, &Bs[p][(h * (BN / 2) + j * 64 + w * 8) * 64]);
    }
  };
  auto LDA = [&](int p, int mh, int kk) {
    #pragma unroll
    for (int m = 0; m < 4; ++m) {
      const int row = mh * 128 + wm2 * 64 + m * 16 + l15;
      af[m] = *(const short8*)&As[p][row * 64 + (((kk * 4 + lg) ^ (row & 7)) * 8)];
    }
  };
  auto LDB = [&](int p, int kk) {
    #pragma unroll
    for (int n = 0; n < NFN; ++n) {
      const int row = wn + n * 16 + l15;
      bf[kk][n] = *(const short8*)&Bs[p][row * 64 + (((kk * 4 + lg) ^ (row & 7)) * 8)];
    }
  };

#define MMQ(MH, KK) \
  __builtin_amdgcn_s_setprio(1); \
  _Pragma("unroll") \
  for (int m = 0; m < 4; ++m) \
    _Pragma("unroll") \
    for (int n = 0; n < NFN; ++n) \
      acc[(MH) * 4 + m][n] = __builtin_amdgcn_mfma_f32_16x16x32_bf16(af[m], bf[KK][n], acc[(MH) * 4 + m][n], 0, 0, 0); \
  __builtin_amdgcn_s_setprio(0);

  STB(0, 0, 0); STB(0, 0, 1); STA(0, 0, 0); STA(0, 0, 1);
  STB(1, 1, 0); STB(1, 1, 1); STA(1, 1, 0);
  VMCNT(VN);
  BARRIER();

  for (int i = 0; i < nt / 2; ++i) {
    const int t = 2 * i;
    const bool li = (i == nt / 2 - 1);
    LDA(0, 0, 0); LDB(0, 0); LDB(0, 1);
    STA(1, t + 1, 1);
    BARRIER(); LGKM0(); SCHED0();
    MMQ(0, 0);
    BARRIER();
    LDA(0, 0, 1);
    if (!li) STB(0, t + 2, 0);
    BARRIER(); LGKM0(); SCHED0();
    MMQ(0, 1);
    BARRIER();
    LDA(0, 1, 0);
    if (!li) STB(0, t + 2, 1);
    BARRIER(); LGKM0(); SCHED0();
    MMQ(1, 0);
    BARRIER();
    LDA(0, 1, 1);
    if (!li) STA(0, t + 2, 0);
    BARRIER(); LGKM0(); SCHED0();
    MMQ(1, 1);
    if (li) { VMCNT(0); } else { VMCNT(VN); }
    BARRIER();
    LDA(1, 0, 0); LDB(1, 0); LDB(1, 1);
    if (!li) STA(0, t + 2, 1);
    BARRIER(); LGKM0(); SCHED0();
    MMQ(0, 0);
    BARRIER();
    LDA(1, 0, 1);
    if (!li) STB(1, t + 3, 0);
    BARRIER(); LGKM0(); SCHED0();
    MMQ(0, 1);
    BARRIER();
    LDA(1, 1, 0);
    if (!li) STB(1, t + 3, 1);
    BARRIER(); LGKM0(); SCHED0();
    MMQ(1, 0);
    BARRIER();
    LDA(1, 1, 1);
    if (!li) STA(1, t + 3, 0);
    BARRIER(); LGKM0(); SCHED0();
    MMQ(1, 1);
    if (!li) { VMCNT(VN); }
    BARRIER();
  }
#undef MMQ

  if (EPI == 4) {
    const int No = N >> 1;
    #pragma unroll
    for (int mf = 0; mf < 8; ++mf) {
      const int r0 = brow + (mf >> 2) * 128 + wm2 * 64 + (mf & 3) * 16 + lg * 4;
      #pragma unroll
      for (int jg = 0; jg < NFN / 2; ++jg) {
        const int c = (bcol >> 1) + (wn >> 1) + jg * 16 + l15;
        #pragma unroll
        for (int i4 = 0; i4 < 4; ++i4) {
          float gt = acc[mf][2 * jg][i4];
          float up = acc[mf][2 * jg + 1][i4];
          ((short*)Cp)[(size_t)(r0 + i4) * No + c] = f2bf(gt / (1.f + __expf(-gt)) * up);
        }
      }
    }
  } else {
    #pragma unroll
    for (int mf = 0; mf < 8; ++mf) {
      const int r0 = brow + (mf >> 2) * 128 + wm2 * 64 + (mf & 3) * 16 + lg * 4;
      #pragma unroll
      for (int nf = 0; nf < NFN; ++nf) {
        const int c = bcol + wn + nf * 16 + l15;
        #pragma unroll
        for (int i4 = 0; i4 < 4; ++i4) {
          const size_t idx = (size_t)(r0 + i4) * N + c;
          float v = acc[mf][nf][i4];
          if (EPI == 0) ((short*)Cp)[idx] = f2bf(v);
          if (EPI == 1) ((float*)Cp)[idx] = v + ((const float*)Xp)[idx];
          if (EPI == 5) ((short*)Cp)[(size_t)blockIdx.z * S_LEN * N + idx] = f2bf(v);
        }
      }
    }
  }
}

// ---------------- RoPE (in-place, K heads only; Q rope fused into attn) ----
__global__ __launch_bounds__(256) void rope_k_kernel(short* __restrict__ qkv,
    const float* __restrict__ cosb, const float* __restrict__ sinb) {
  int idx = blockIdx.x * 256 + threadIdx.x;
  int d = idx & 31;
  int hh = (idx >> 5) & (NKV - 1);
  int s = idx >> 8;
  short* base = qkv + (size_t)s * QKVLD + HIDN + hh * HD;
  float c  = cosb[s * HD + d];
  float sn = sinb[s * HD + d];
  float x1 = bf2f(base[d]), x2 = bf2f(base[d + 32]);
  base[d]      = f2bf(x1 * c - x2 * sn);
  base[d + 32] = f2bf(x2 * c + x1 * sn);
}

// ---------------- Flash attention: swapped 32x32x16, KVBLK=128, fused Q-rope,
// XOR-swizzled K/V LDS (conflict-free reads), paired-b32 V-transpose writes ----
__global__ __launch_bounds__(256) void attn_kernel(const short* __restrict__ QKV,
    const float* __restrict__ cosb, const float* __restrict__ sinb,
    short* __restrict__ O) {
  __shared__ __align__(16) short Ks[128 * 64];   // row-major, 16B-block swizzle ^(row&7)
  __shared__ __align__(16) short VTs[64 * 128];  // [d][k], 16B-block swizzle ^(d&7)
  const int bid = blockIdx.x;
  const int half_ = bid >> 8, idx = bid & 255;
  const int h = idx & 31;
  int qt = idx >> 5;
  qt = half_ ? (15 - qt) : qt;
  const int kvh = h >> 2;
  const int tid = threadIdx.x, lane = tid & 63, w = tid >> 6;
  const int l31 = lane & 31, hi = lane >> 5;
  const int qb = qt * 128 + w * 32;
  const int kcol = HIDN + kvh * HD;
  const int vcol = HIDN + NKV * HD + kvh * HD;

  // Q load + fused rope + 1/8 scale
  short8 Qr[4];
  {
    const int s = qb + l31;
    const short* qp = QKV + (size_t)s * QKVLD + h * HD;
    short8 qv[4];
    #pragma unroll
    for (int dk = 0; dk < 4; ++dk) qv[dk] = *(const short8*)(qp + dk * 16 + hi * 8);
    const float* cp = cosb + s * HD;
    const float* sp = sinb + s * HD;
    #pragma unroll
    for (int dk = 0; dk < 2; ++dk)
      #pragma unroll
      for (int e = 0; e < 8; ++e) {
        const int d = dk * 16 + hi * 8 + e;
        float c = cp[d], sn = sp[d];
        float x1 = bf2f(qv[dk][e]), x2 = bf2f(qv[dk + 2][e]);
        Qr[dk][e]     = f2bf((x1 * c - x2 * sn) * 0.125f);
        Qr[dk + 2][e] = f2bf((x2 * c + x1 * sn) * 0.125f);
      }
  }
  float m_ = -3e38f, l_ = 0.f;
  f32x16 o0 = {}, o1 = {};
  const int nt = qt + 1;               // 128-wide KV tiles
  const int kr_ = tid >> 1, kdb1 = (tid & 1);
  const int va_ = tid & 63, vdb = (tid >> 6) * 16;

  short8 kp0, kp1, kp2, kp3, vp0, vp1, vp2, vp3;
  {
    const short* gk = QKV + (size_t)kr_ * QKVLD + kcol + kdb1 * 32;
    kp0 = *(const short8*)gk;        kp1 = *(const short8*)(gk + 8);
    kp2 = *(const short8*)(gk + 16); kp3 = *(const short8*)(gk + 24);
    const short* gv0 = QKV + (size_t)(2 * va_) * QKVLD + vcol + vdb;
    const short* gv1 = QKV + (size_t)(2 * va_ + 1) * QKVLD + vcol + vdb;
    vp0 = *(const short8*)gv0; vp1 = *(const short8*)(gv0 + 8);
    vp2 = *(const short8*)gv1; vp3 = *(const short8*)(gv1 + 8);
  }

  for (int t = 0; t < nt; ++t) {
    const int kb = t * 128;
    BARRIER();                     // prev compute done
    {
      short* kbase_ = Ks + kr_ * 64;
      const int rs = kr_ & 7;
      *(short8*)(kbase_ + ((kdb1 * 4 + 0) ^ rs) * 8) = kp0;
      *(short8*)(kbase_ + ((kdb1 * 4 + 1) ^ rs) * 8) = kp1;
      *(short8*)(kbase_ + ((kdb1 * 4 + 2) ^ rs) * 8) = kp2;
      *(short8*)(kbase_ + ((kdb1 * 4 + 3) ^ rs) * 8) = kp3;
      const int kblk = (2 * va_) >> 3, kin = (2 * va_) & 7;
      #pragma unroll
      for (int j = 0; j < 8; ++j) {
        const int d0 = vdb + j;
        *(unsigned*)(VTs + d0 * 128 + ((kblk ^ (d0 & 7)) * 8) + kin) = packs2(vp0[j], vp2[j]);
        const int d1 = vdb + 8 + j;
        *(unsigned*)(VTs + d1 * 128 + ((kblk ^ (d1 & 7)) * 8) + kin) = packs2(vp1[j], vp3[j]);
      }
    }
    LGKM0();                       // LDS writes visible
    BARRIER();
    if (t + 1 < nt) {              // async prefetch next tile under compute
      const int kb2 = kb + 128;
      const short* gk = QKV + (size_t)(kb2 + kr_) * QKVLD + kcol + kdb1 * 32;
      kp0 = *(const short8*)gk;        kp1 = *(const short8*)(gk + 8);
      kp2 = *(const short8*)(gk + 16); kp3 = *(const short8*)(gk + 24);
      const short* gv0 = QKV + (size_t)(kb2 + 2 * va_) * QKVLD + vcol + vdb;
      const short* gv1 = QKV + (size_t)(kb2 + 2 * va_ + 1) * QKVLD + vcol + vdb;
      vp0 = *(const short8*)gv0; vp1 = *(const short8*)(gv0 + 8);
      vp2 = *(const short8*)gv1; vp3 = *(const short8*)(gv1 + 8);
    }
    #pragma unroll
    for (int hf = 0; hf < 2; ++hf) {
      const int hb = kb + hf * 64;
      if (hb < qb + 32) {
        f32x16 s[2] = {};
        __builtin_amdgcn_s_setprio(1);
        #pragma unroll
        for (int kt = 0; kt < 2; ++kt) {
          const int row = hf * 64 + kt * 32 + l31;
          #pragma unroll
          for (int dk = 0; dk < 4; ++dk) {
            short8 kf = *(const short8*)(Ks + row * 64 + (((dk * 2 + hi) ^ (row & 7)) * 8));
            s[kt] = __builtin_amdgcn_mfma_f32_32x32x16_bf16(kf, Qr[dk], s[kt], 0, 0, 0);
          }
        }
        __builtin_amdgcn_s_setprio(0);
        if (hb + 63 > qb) {
          const int qg = qb + l31;
          #pragma unroll
          for (int kt = 0; kt < 2; ++kt)
            #pragma unroll
            for (int r = 0; r < 16; ++r) {
              const int kg = hb + kt * 32 + (r & 3) + 8 * (r >> 2) + 4 * hi;
              if (kg > qg) s[kt][r] = -1e30f;
            }
        }
        float pm = s[0][0];
        #pragma unroll
        for (int r = 1; r < 16; ++r) pm = fmaxf(pm, s[0][r]);
        #pragma unroll
        for (int r = 0; r < 16; ++r) pm = fmaxf(pm, s[1][r]);
        pm = fmaxf(pm, __shfl_xor(pm, 32));
        const float mn = fmaxf(m_, pm);
        const float al = __expf(m_ - mn);
        float rsum = 0.f;
        #pragma unroll
        for (int kt = 0; kt < 2; ++kt)
          #pragma unroll
          for (int r = 0; r < 16; ++r) { s[kt][r] = __expf(s[kt][r] - mn); rsum += s[kt][r]; }
        rsum += __shfl_xor(rsum, 32);
        l_ = l_ * al + rsum;
        m_ = mn;
        o0 *= al; o1 *= al;
        unsigned wd[2][8], rw[2][8];
        #pragma unroll
        for (int kt = 0; kt < 2; ++kt)
          #pragma unroll
          for (int i = 0; i < 8; ++i) {
            wd[kt][i] = packbf2(s[kt][2 * i], s[kt][2 * i + 1]);
            rw[kt][i] = (unsigned)__shfl_xor((int)wd[kt][i], 32);
          }
        #pragma unroll
        for (int kt = 0; kt < 2; ++kt) {
          union { unsigned u[4]; short8 s8; } pf0, pf1;
          if (hi) {
            pf0.u[0] = rw[kt][2]; pf0.u[1] = rw[kt][3]; pf0.u[2] = wd[kt][2]; pf0.u[3] = wd[kt][3];
            pf1.u[0] = rw[kt][6]; pf1.u[1] = rw[kt][7]; pf1.u[2] = wd[kt][6]; pf1.u[3] = wd[kt][7];
          } else {
            pf0.u[0] = wd[kt][0]; pf0.u[1] = wd[kt][1]; pf0.u[2] = rw[kt][0]; pf0.u[3] = rw[kt][1];
            pf1.u[0] = wd[kt][4]; pf1.u[1] = wd[kt][5]; pf1.u[2] = rw[kt][4]; pf1.u[3] = rw[kt][5];
          }
          __builtin_amdgcn_s_setprio(1);
          #pragma unroll
          for (int ks = 0; ks < 2; ++ks) {
            const short8 pB = ks ? pf1.s8 : pf0.s8;
            const int blk = hf * 8 + kt * 4 + ks * 2 + hi;
            const int d0 = l31, d1 = 32 + l31;
            short8 va = *(const short8*)(VTs + d0 * 128 + ((blk ^ (d0 & 7)) * 8));
            o0 = __builtin_amdgcn_mfma_f32_32x32x16_bf16(va, pB, o0, 0, 0, 0);
            short8 vb = *(const short8*)(VTs + d1 * 128 + ((blk ^ (d1 & 7)) * 8));
            o1 = __builtin_amdgcn_mfma_f32_32x32x16_bf16(vb, pB, o1, 0, 0, 0);
          }
          __builtin_amdgcn_s_setprio(0);
        }
      }
    }
  }
  const float inv = 1.f / l_;
  short* op = O + (size_t)(qb + l31) * HIDN + h * HD;
  #pragma unroll
  for (int dt = 0; dt < 2; ++dt) {
    const f32x16& o = dt ? o1 : o0;
    #pragma unroll
    for (int g = 0; g < 4; ++g) {
      s16x4 st;
      st[0] = f2bf(o[g * 4 + 0] * inv);
      st[1] = f2bf(o[g * 4 + 1] * inv);
      st[2] = f2bf(o[g * 4 + 2] * inv);
      st[3] = f2bf(o[g * 4 + 3] * inv);
      *(s16x4*)(op + dt * 32 + g * 8 + hi * 4) = st;
    }
  }
}

// ---------------- out += sum of 4 bf16 split-K partials ----------------
__global__ __launch_bounds__(256) void reduce4_kernel(float* __restrict__ out,
    const short* __restrict__ P) {
  const size_t n = (size_t)S_LEN * HIDN;
  size_t i = ((size_t)blockIdx.x * 256 + threadIdx.x) * 4;
  float4 o = *(float4*)(out + i);
  float s0 = 0.f, s1 = 0.f, s2 = 0.f, s3 = 0.f;
  #pragma unroll
  for (int z = 0; z < 4; ++z) {
    s16x4 p = *(const s16x4*)(P + z * n + i);
    s0 += bf2f(p[0]); s1 += bf2f(p[1]); s2 += bf2f(p[2]); s3 += bf2f(p[3]);
  }
  o.x += s0; o.y += s1; o.z += s2; o.w += s3;
  *(float4*)(out + i) = o;
}

extern "C" void kernel_launch(void* const* d_in, const int* in_sizes, int n_in,
                              void* d_out, int out_size, void* d_ws, size_t ws_size,
                              hipStream_t stream) {
  const float* hs   = (const float*)d_in[0];
  const float* cosb = (const float*)d_in[1];
  const float* sinb = (const float*)d_in[2];
  const float* wq   = (const float*)d_in[3];
  const float* wk   = (const float*)d_in[4];
  const float* wv   = (const float*)d_in[5];
  const float* wo   = (const float*)d_in[6];
  const float* wln1 = (const float*)d_in[7];
  const float* wln2 = (const float*)d_in[8];
  const float* wg   = (const float*)d_in[9];
  const float* wu   = (const float*)d_in[10];
  const float* wd   = (const float*)d_in[11];
  float* out = (float*)d_out;
  char* ws = (char*)d_ws;
  const size_t MB = 1024 * 1024;
  // ws layout (104 MB, R13-verified):
  //  Wqkv@0 (12.6) -> dead after QKV gemm; Pwo@0 (16) after attn; Wbig@0 (64); Wd@0 (32)
  //  xn@13 (8) -> dead after QKV gemm
  //  qkv@21 (12.6) -> dead after attn
  //  attnO@34 (8); Wwo@42 (8); y@64 (8); g@72 (32); P@32 (32, 4 bf16 planes)
  short* Wqkv  = (short*)(ws);
  short* xn    = (short*)(ws + 13 * MB);
  short* qkv   = (short*)(ws + 21 * MB);
  short* attnO = (short*)(ws + 34 * MB);
  short* Wwo   = (short*)(ws + 42 * MB);
  short* Pwo   = (short*)(ws);
  short* y     = (short*)(ws + 64 * MB);
  short* g     = (short*)(ws + 72 * MB);
  short* Wbig  = (short*)(ws);
  short* Wd    = (short*)(ws);
  short* P     = (short*)(ws + 32 * MB);

  convT4_kernel<<<dim3(32, 32, 4), 256, 0, stream>>>(wq, wk, wv, wo, Wqkv, Wwo);
  rmsnorm_kernel<<<S_LEN, 256, 0, stream>>>(hs, wln1, xn);
  gemm8p<0, 128><<<dim3(192, 1, 1), 512, 0, stream>>>(xn, Wqkv, qkv, nullptr, QKVN, HIDN, HIDN, 24);
  rope_k_kernel<<<(S_LEN * NKV * 32) / 256, 256, 0, stream>>>(qkv, cosb, sinb);
  attn_kernel<<<NH * (S_LEN / 128), 256, 0, stream>>>(qkv, cosb, sinb, attnO);
  gemm8p<5, 128><<<dim3(128, 1, 2), 512, 0, stream>>>(attnO, Wwo, Pwo, nullptr, HIDN, NH * HD, NH * HD / 2, 16);
  wo_norm_kernel<<<S_LEN, 256, 0, stream>>>(out, hs, Pwo, wln2, y);
  convT_pack2_kernel<<<dim3(32, 128, 2), 256, 0, stream>>>(wg, wu, Wbig);
  gemm8p<4, 256><<<dim3(512, 1, 1), 512, 0, stream>>>(y, Wbig, g, nullptr, 2 * FFN, HIDN, HIDN, 64);
  convT_kernel<<<dim3(128, 32), 256, 0, stream>>>(wd, Wd, FFN, HIDN);
  gemm8p<5, 256><<<dim3(64, 1, 4), 512, 0, stream>>>(g, Wd, P, nullptr, HIDN, FFN, FFN / 4, 8);
  reduce4_kernel<<<(S_LEN * HIDN) / 1024, 256, 0, stream>>>(out, P);
}